// Round 21
// baseline (260.767 us; speedup 1.0000x reference)
//
#include <hip/hip_runtime.h>
#include <stdint.h>

typedef __bf16 bf16x8 __attribute__((ext_vector_type(8)));
typedef float f32x4 __attribute__((ext_vector_type(4)));
typedef uint32_t u32x4 __attribute__((ext_vector_type(4)));

#define MFMA16(a,b,c) __builtin_amdgcn_mfma_f32_16x16x32_bf16(a,b,c,0,0,0)

// ---------------- workspace layout (bytes) ----------------
#define OFF_XB   0ull           // X bf16 [16384][256]              8,388,608
#define OFF_WT   8388608ull     // WqT/WkT/WvT bf16 [3][2048][256]  3,145,728
#define OFF_WTT  11534336ull    // Wq_tT/Wk_tT/Wv_tT same           3,145,728
#define OFF_WOT  14680064ull    // WoT bf16 [256][2048]             1,048,576
#define OFF_MB   15728640ull    // mish(t+r) bf16 [64][256]            32,768
#define OFF_BIAS 15761408ull    // bias fp32 [3][64][2048]          1,572,864
#define OFF_K    17334272ull    // K bf16 [512][256 l][256 d]      67,108,864
#define OFF_VT   84443136ull    // V^T bf16 [512][256 d][256 l]    67,108,864
#define WS_NEED  151552000ull   // minimum (fallback path)
#define OFF_Q    151552000ull   // Q bf16 [512][256 l][256 d] -- O overwrites in place
#define WS_NEED2 218660864ull   // full pipeline (confirmed available in r10)

__device__ __forceinline__ uint16_t f2bf(float f) {
  uint32_t u = __builtin_bit_cast(uint32_t, f);
  return (uint16_t)((u + 0x7fffu + ((u >> 16) & 1u)) >> 16);
}
__device__ __forceinline__ bf16x8 ld16(const uint16_t* p) {
  u32x4 v = *(const u32x4*)p;
  return __builtin_bit_cast(bf16x8, v);
}
// async global->LDS, 16B per lane; LDS dest is wave-uniform base + lane*16
__device__ __forceinline__ void gll16(const uint16_t* g, char* l) {
  __builtin_amdgcn_global_load_lds(
      (const __attribute__((address_space(1))) void*)g,
      (__attribute__((address_space(3))) void*)l, 16, 0, 0);
}
// per-wave 4KB bounce slab (fallback attn): [16 rows][128 bf16], pitch 256B, swz
__device__ __forceinline__ void bounce_w2(char* slab, int row, int col, uint16_t val) {
  int slot = col >> 3;
  *(uint16_t*)(slab + row * 256 + (((slot ^ (row & 7)) & 15) << 4) + ((col & 7) << 1)) = val;
}
__device__ __forceinline__ bf16x8 bounce_r16(const char* slab, int row, int slot) {
  u32x4 v = *(const u32x4*)(slab + row * 256 + (((slot ^ (row & 7)) & 15) << 4));
  return __builtin_bit_cast(bf16x8, v);
}

// ---------------- ws-size sentinel + output init ----------------
__global__ void sentinel_kernel(float* out, float val) {
  out[blockIdx.x * 256 + threadIdx.x] = val;
}
__global__ void init_out(const float* bo, float* out) {
  int i = blockIdx.x * 256 + threadIdx.x;
  out[i] = bo[i & 255];
}

// ---------------- fused prep: mish + convx + wtrans in one launch ----------------
__global__ void prep_all(const float* te, const float* re, uint16_t* mb,
                         const float* x, uint16_t* xb,
                         const float* w0, const float* w1, const float* w2,
                         const float* w3, const float* w4, const float* w5,
                         const float* w6, uint16_t* wt, uint16_t* wtt, uint16_t* wot) {
  int b = blockIdx.x;
  if (b < 64) {
    int i = b * 256 + threadIdx.x;
    float v = te[i] + re[i];
    float sp = log1pf(__expf(v));
    mb[i] = f2bf(v * tanhf(sp));
    return;
  }
  if (b < 4160) {
    int i = (b - 64) * 256 + threadIdx.x;
    float4 v = ((const float4*)x)[i];
    ushort4 o = make_ushort4(f2bf(v.x), f2bf(v.y), f2bf(v.z), f2bf(v.w));
    ((ushort4*)xb)[i] = o;
    return;
  }
  int local = b - 4160;
  int z = local >> 9, bx = local & 511;
  const float* src; uint16_t* dst; int C;
  if (z < 3)      { src = (z==0)?w0:((z==1)?w1:w2); dst = wt  + (size_t)z*524288;     C=2048; }
  else if (z < 6) { src = (z==3)?w3:((z==4)?w4:w5); dst = wtt + (size_t)(z-3)*524288; C=2048; }
  else            { src = w6; dst = wot;                                              C=256; }
  int R = (z < 6) ? 256 : 2048;
  __shared__ uint16_t tile[32][33];
  int tc = C >> 5;
  int bR = (bx / tc) << 5, bC = (bx % tc) << 5;
  int tx = threadIdx.x & 31, ty = threadIdx.x >> 5;  // 32 x 8
  #pragma unroll
  for (int i = 0; i < 4; i++) {
    int r = bR + ty + i * 8;
    tile[ty + i * 8][tx] = f2bf(src[(size_t)r * C + bC + tx]);
  }
  __syncthreads();
  #pragma unroll
  for (int i = 0; i < 4; i++) {
    int c = bC + ty + i * 8;
    dst[(size_t)c * R + bR + tx] = tile[tx][ty + i * 8];
  }
}

// ---------------- bias GEMM (no LDS): [3] x (m[64x256] @ Wt[256x2048] + b) -> fp32 ----------------
__global__ __launch_bounds__(256, 4)
void bias_gemm(const uint16_t* Mb, const uint16_t* WTT,
               const float* bq, const float* bk, const float* bv, float* biasAll) {
  int bid = blockIdx.x;            // 48 = 3 * 16
  int z = bid >> 4, nbt = bid & 15;
  int n0 = nbt << 7;
  const uint16_t* Bsrc = WTT + (size_t)z * 524288;
  const float* bvec = (z == 0) ? bq : ((z == 1) ? bk : bv);
  float* outp = biasAll + (size_t)z * 131072;
  int tid = threadIdx.x, lane = tid & 63, w = tid >> 6;
  int g = lane >> 4, ln = lane & 15;

  bf16x8 af[8];
  #pragma unroll
  for (int ks = 0; ks < 8; ks++)
    af[ks] = ld16(Mb + (size_t)(w*16 + ln) * 256 + ks*32 + g*8);
  f32x4 acc[8];
  #pragma unroll
  for (int j = 0; j < 8; j++) acc[j] = (f32x4){0.f,0.f,0.f,0.f};
  #pragma unroll
  for (int j = 0; j < 8; j++)
    #pragma unroll
    for (int ks = 0; ks < 8; ks++) {
      bf16x8 bf_ = ld16(Bsrc + (size_t)(n0 + j*16 + ln) * 256 + ks*32 + g*8);
      acc[j] = MFMA16(af[ks], bf_, acc[j]);
    }
  #pragma unroll
  for (int j = 0; j < 8; j++) {
    int colg = n0 + j*16 + ln;
    float bb = bvec[colg];
    #pragma unroll
    for (int r = 0; r < 4; r++)
      outp[(size_t)(w*16 + g*4 + r) * 2048 + colg] = acc[j][r] + bb;
  }
}

// ---------------- QKV GEMM v8: BM=256 (one bt per block), shared-B m-loop ----------------
// grid 3072 = 3 z * 64 mt * 16 nt (full) or 2048 (fallback: K,V only). block 256, 4 waves.
// Per K-step: stage A [256][64] (32KB) + B [128][64] (16KB, shared by both m-halves)
// -> 64 MFMAs/wave per barrier pair (2x r20), B traffic per output halved.
__global__ __launch_bounds__(256)
void qkv_gemm5(const uint16_t* Xb, const uint16_t* WT, const float* biasAll,
               uint16_t* Kw, uint16_t* Vt, uint16_t* Qw) {
  __shared__ char stage[49152];          // [0,32K) A; [32K,48K) B; epilogue slabs reuse [0,32K)
  int nwg = gridDim.x, cpx = nwg >> 3;
  int b0 = blockIdx.x;
  int bid = (b0 & 7) * cpx + (b0 >> 3);  // XCD-aware bijective swizzle (nwg%8==0)
  int z2 = bid >> 10, rem = bid & 1023;  // z2: 0=K, 1=V, 2=Q ; rem = mt*16 + nb
  int widx = (z2 + 1) % 3;               // weight: 1=Wk, 2=Wv, 0=Wq
  int mt = rem >> 4, nb = rem & 15;
  int m0 = mt << 8, n0 = nb << 7;        // 256-row (one bt) x 128-col tile
  const uint16_t* Bsrc = WT + (size_t)widx * 524288;
  int bt = mt;                           // m0 >> 8
  const float* bias = biasAll + (size_t)widx * 131072 + (size_t)bt * 2048;
  int tid = threadIdx.x, lane = tid & 63, w = tid >> 6;
  int g = lane >> 4, ln = lane & 15;
  int wr = w >> 1, wc = w & 1;           // wave quadrant within a 128x128 half
  int rw = lane >> 3;                    // row within 1KB chunk (0..7)
  int sg = (lane & 7) ^ rw;              // source-swizzled 16B slot

  f32x4 acc[2][4][4];
  #pragma unroll
  for (int mh = 0; mh < 2; mh++)
    #pragma unroll
    for (int i = 0; i < 4; i++)
      #pragma unroll
      for (int j = 0; j < 4; j++) acc[mh][i][j] = (f32x4){0.f,0.f,0.f,0.f};

  for (int kt = 0; kt < 4; kt++) {
    int k0 = kt << 6;
    __syncthreads();
    #pragma unroll
    for (int c = 0; c < 8; c++) {        // A: 32 chunks (256 rows); 8 per wave
      int chunk = w * 8 + c;
      int row = chunk * 8 + rw;
      gll16(Xb + (size_t)(m0 + row) * 256 + k0 + sg * 8, stage + chunk * 1024);
    }
    #pragma unroll
    for (int c = 0; c < 4; c++) {        // B: 16 chunks (128 rows); 4 per wave
      int chunk = w * 4 + c;
      int row = chunk * 8 + rw;
      gll16(Bsrc + (size_t)(n0 + row) * 256 + k0 + sg * 8, stage + 32768 + chunk * 1024);
    }
    __syncthreads();                     // compiler drains vmcnt before barrier
    #pragma unroll
    for (int ks = 0; ks < 2; ks++) {
      bf16x8 fb[4];
      #pragma unroll
      for (int j = 0; j < 4; j++) {
        int R = wc*64 + j*16 + ln;
        u32x4 v = *(const u32x4*)(stage + 32768 + R*128 + ((((ks<<1)*2+g) ^ (R & 7)) << 4));
        fb[j] = __builtin_bit_cast(bf16x8, v);
      }
      #pragma unroll
      for (int mh = 0; mh < 2; mh++) {
        bf16x8 fa[4];
        #pragma unroll
        for (int i = 0; i < 4; i++) {
          int R = mh*128 + wr*64 + i*16 + ln;
          u32x4 v = *(const u32x4*)(stage + R*128 + ((((ks<<2)+g) ^ (R & 7)) << 4));
          fa[i] = __builtin_bit_cast(bf16x8, v);
        }
        #pragma unroll
        for (int j = 0; j < 4; j++)
          #pragma unroll
          for (int i = 0; i < 4; i++)
            acc[mh][i][j] = MFMA16(fa[i], fb[j], acc[mh][i][j]);
      }
    }
  }

  // ---- epilogue per m-half: proven bounce -> coalesced 16B stores ----
  __syncthreads();                       // all stage reads done; reuse [0,32K) as slabs
  char* esl = stage + (w << 13);         // per-wave 8KB slab [64][64] bf16, pitch 128B
  float scale = (z2 == 2) ? 0.0625f : 1.0f;
  int hh = n0 >> 8;
  size_t hb = (size_t)(bt * 8 + hh) << 16;
  int dbase = (n0 & 255) + wc*64;

  #pragma unroll
  for (int mh = 0; mh < 2; mh++) {
    int lbase = mh*128 + wr*64;
    if (z2 == 1) {
      // V: slab row = d (j*16+ln); 4 contiguous l per fragment -> packed 8B writes
      #pragma unroll
      for (int j = 0; j < 4; j++) {
        float bb = bias[n0 + wc*64 + j*16 + ln];
        int row = j*16 + ln;
        #pragma unroll
        for (int i = 0; i < 4; i++) {
          int col0 = i*16 + g*4;
          ushort4 pk = make_ushort4(f2bf(acc[mh][i][j][0]+bb), f2bf(acc[mh][i][j][1]+bb),
                                    f2bf(acc[mh][i][j][2]+bb), f2bf(acc[mh][i][j][3]+bb));
          *(ushort4*)(esl + row*128 + ((((col0 >> 3) ^ (row & 7)) & 7) << 4)
                      + ((col0 & 7) << 1)) = pk;
        }
      }
    } else {
      // K/Q: slab row = l; scalar writes (r15-proven layout)
      #pragma unroll
      for (int j = 0; j < 4; j++) {
        float bb = bias[n0 + wc*64 + j*16 + ln];
        int slotb = j*2 + (ln >> 3), bcol = (ln & 7) << 1;
        #pragma unroll
        for (int i = 0; i < 4; i++)
          #pragma unroll
          for (int r = 0; r < 4; r++) {
            int row = i*16 + g*4 + r;
            *(uint16_t*)(esl + row*128 + (((slotb ^ (row & 7)) & 7) << 4) + bcol)
                = f2bf((acc[mh][i][j][r] + bb) * scale);
          }
      }
    }
    // same-wave coalesced readback: 8 x 16B stores per thread
    #pragma unroll
    for (int it = 0; it < 8; it++) {
      int idx = it*64 + lane;
      int row = idx >> 3, ch = idx & 7;
      u32x4 v = *(const u32x4*)(esl + row*128 + (((ch ^ (row & 7)) & 7) << 4));
      if (z2 == 1) {      // V^T: [d][l]
        *(u32x4*)(Vt + hb + ((size_t)(dbase + row) << 8) + lbase + ch*8) = v;
      } else {            // K/Q: [l][d]
        uint16_t* dst = (z2 == 0) ? Kw : Qw;
        *(u32x4*)(dst + hb + ((size_t)(lbase + row) << 8) + dbase + ch*8) = v;
      }
    }
  }
}

// ---------------- attn core v2 (proven): reg-staged K/V; O overwrites Q in place ----------------
__global__ __launch_bounds__(1024, 2)
void attn_core2(const uint16_t* Qw, const uint16_t* Kw, const uint16_t* Vt, uint16_t* Ob) {
  __shared__ char smem[65536];
  int tid = threadIdx.x, lane = tid & 63, w = tid >> 6;   // w in 0..15
  int g = lane >> 4, ln = lane & 15;
  int bh = blockIdx.x;                       // 512 blocks
  const size_t kvbase = (size_t)bh << 16;
  int q0l = w * 16;
  char* stage = smem;
  char* slab  = smem + 32768 + (w << 11);

  u32x4 rv[2];
  auto issue_tile = [&](const uint16_t* src) {
    #pragma unroll
    for (int it = 0; it < 2; it++) {
      int c = tid + (it << 10);
      int row = c >> 5, sl = c & 31;
      rv[it] = *(const u32x4*)(src + (size_t)row * 256 + sl * 8);
    }
  };
  auto commit_tile = [&]() {
    #pragma unroll
    for (int it = 0; it < 2; it++) {
      int c = tid + (it << 10);
      int row = c >> 5, sl = c & 31;
      *(u32x4*)(stage + row * 512 + ((sl ^ (row & 7)) << 4)) = rv[it];
    }
  };
  auto frag = [&](int row, int slot) -> bf16x8 {
    u32x4 v = *(const u32x4*)(stage + row * 512 + ((slot ^ (row & 7)) << 4));
    return __builtin_bit_cast(bf16x8, v);
  };

  issue_tile(Kw + kvbase);
  bf16x8 qa[8];
  #pragma unroll
  for (int ks = 0; ks < 8; ks++)
    qa[ks] = ld16(Qw + kvbase + (size_t)(q0l + ln) * 256 + ks*32 + g*8);

  f32x4 S[16];
  #pragma unroll
  for (int f = 0; f < 16; f++) S[f] = (f32x4){0.f,0.f,0.f,0.f};
  #pragma unroll
  for (int t = 0; t < 4; t++) {
    __syncthreads();
    commit_tile();
    __syncthreads();
    if (t < 3) issue_tile(Kw + kvbase + (size_t)((t+1)*64) * 256);
    #pragma unroll
    for (int ks = 0; ks < 8; ks++)
      #pragma unroll
      for (int f2 = 0; f2 < 4; f2++)
        S[t*4+f2] = MFMA16(qa[ks], frag(f2*16 + ln, ks*4 + g), S[t*4+f2]);
  }
  issue_tile(Vt + kvbase);

  #pragma unroll
  for (int r = 0; r < 4; r++) {
    float mx = -3.4e38f;
    #pragma unroll
    for (int f = 0; f < 16; f++) mx = fmaxf(mx, S[f][r]);
    #pragma unroll
    for (int m_ = 1; m_ < 16; m_ <<= 1) mx = fmaxf(mx, __shfl_xor(mx, m_, 64));
    float sum = 0.f;
    #pragma unroll
    for (int f = 0; f < 16; f++) {
      float p = __expf(S[f][r] - mx);
      S[f][r] = p; sum += p;
    }
    #pragma unroll
    for (int m_ = 1; m_ < 16; m_ <<= 1) sum += __shfl_xor(sum, m_, 64);
    float inv = 1.f / sum;
    #pragma unroll
    for (int f = 0; f < 16; f++) S[f][r] *= inv;
  }

  bf16x8 pb[8];
  #pragma unroll
  for (int qtr = 0; qtr < 4; qtr++) {
    #pragma unroll
    for (int f2 = 0; f2 < 4; f2++) {
      int col = f2*16 + ln;
      int slot = col >> 3;
      #pragma unroll
      for (int r = 0; r < 4; r++) {
        int row = g*4 + r;
        *(uint16_t*)(slab + row*128 + (((slot ^ (row & 7)) & 7) << 4) + ((col & 7) << 1))
            = f2bf(S[qtr*4+f2][r]);
      }
    }
    #pragma unroll
    for (int i = 0; i < 2; i++) {
      u32x4 v = *(const u32x4*)(slab + ln*128 + ((((i*4+g) ^ (ln & 7)) & 7) << 4));
      pb[qtr*2+i] = __builtin_bit_cast(bf16x8, v);
    }
  }

  f32x4 O[16];
  #pragma unroll
  for (int df = 0; df < 16; df++) O[df] = (f32x4){0.f,0.f,0.f,0.f};
  #pragma unroll
  for (int t = 0; t < 4; t++) {
    __syncthreads();
    commit_tile();
    __syncthreads();
    if (t < 3) issue_tile(Vt + kvbase + (size_t)((t+1)*64) * 256);
    #pragma unroll
    for (int ks = 0; ks < 8; ks++)
      #pragma unroll
      for (int df2 = 0; df2 < 4; df2++)
        O[t*4+df2] = MFMA16(frag(df2*16 + ln, ks*4 + g), pb[ks], O[t*4+df2]);
  }

  size_t obase = kvbase + (size_t)(q0l + ln) * 256;
  #pragma unroll
  for (int df = 0; df < 16; df++) {
    ushort4 pk = make_ushort4(f2bf(O[df][0]), f2bf(O[df][1]), f2bf(O[df][2]), f2bf(O[df][3]));
    *(ushort4*)(Ob + obase + df*16 + g*4) = pk;
  }
}

// ---------------- out GEMM: O (bh,l,d) @ Wo + bo -> fp32 out; A+B prefetched; XCD swizzle ----------------
__global__ __launch_bounds__(256, 4)
void out_gemm(const uint16_t* Ob, const uint16_t* WoT, const float* bo, float* out) {
  __shared__ char stage[16384];
  int b0 = blockIdx.x;
  int bid = (b0 & 7) * 64 + (b0 >> 3);
  int mt = bid >> 1, nt = bid & 1;
  int m0 = mt << 6, n0 = nt << 7;
  int bt = m0 >> 8;
  int lrow = (m0 & 255);
  int tid = threadIdx.x, lane = tid & 63, w = tid >> 6;
  int g = lane >> 4, ln = lane & 15;

  u32x4 rb[4];
  auto issueW = [&](int kt) {
    #pragma unroll
    for (int it = 0; it < 4; it++) {
      int c = tid + (it << 8);
      int row = c >> 3, sl = c & 7;
      rb[it] = *(const u32x4*)(WoT + (size_t)(n0 + row) * 2048 + kt*64 + sl*8);
    }
  };
  auto aptr = [&](int kt) -> const uint16_t* {
    return Ob + ((size_t)(bt*8 + (kt >> 2)) << 16)
         + (size_t)(lrow + w*16 + ln) * 256 + (kt & 3) * 64;
  };
  issueW(0);
  bf16x8 afc[2];
  { const uint16_t* ab = aptr(0); afc[0] = ld16(ab + g*8); afc[1] = ld16(ab + 32 + g*8); }
  f32x4 acc[8];
  #pragma unroll
  for (int j = 0; j < 8; j++) acc[j] = (f32x4){0.f,0.f,0.f,0.f};

  for (int kt = 0; kt < 32; kt++) {
    __syncthreads();
    #pragma unroll
    for (int it = 0; it < 4; it++) {
      int c = tid + (it << 8);
      int row = c >> 3, sl = c & 7;
      *(u32x4*)(stage + row*128 + (((sl ^ (row & 7)) & 7) << 4)) = rb[it];
    }
    __syncthreads();
    bf16x8 afn[2];
    if (kt < 31) {
      issueW(kt+1);
      const uint16_t* ab = aptr(kt+1);
      afn[0] = ld16(ab + g*8); afn[1] = ld16(ab + 32 + g*8);
    }
    #pragma unroll
    for (int ks = 0; ks < 2; ks++)
      #pragma unroll
      for (int j = 0; j < 8; j++) {
        int row = j*16 + ln;
        u32x4 v = *(const u32x4*)(stage + row*128 + ((((ks*4+g) ^ (row & 7)) & 7) << 4));
        acc[j] = MFMA16(afc[ks], __builtin_bit_cast(bf16x8, v), acc[j]);
      }
    if (kt < 31) { afc[0] = afn[0]; afc[1] = afn[1]; }
  }
  #pragma unroll
  for (int j = 0; j < 8; j++) {
    int col = n0 + j*16 + ln;
    float bb = bo[col];
    #pragma unroll
    for (int r = 0; r < 4; r++)
      out[(size_t)(m0 + w*16 + g*4 + r) * 256 + col] = acc[j][r] + bb;
  }
}

// ---------------- fallback fused attention (proven round-9 path) ----------------
__global__ __launch_bounds__(512, 2)
void attn_v5(const uint16_t* Xb, const uint16_t* WT, const float* Bi,
             const uint16_t* Kw, const uint16_t* Vt, const uint16_t* WoT,
             float* out) {
  __shared__ char smem[65536];
  int tid = threadIdx.x, lane = tid & 63, w = tid >> 6;
  int g = lane >> 4, ln = lane & 15;
  int bid = blockIdx.x;
  int bh = bid >> 1, qh = bid & 1;
  int bt = bh >> 3, h = bh & 7;
  const size_t kvbase = (size_t)bh << 16;
  int q0g = bt * 256 + qh * 128 + w * 16;
  char* stage = smem;
  char* slab  = smem + 32768 + (w << 12);

  u32x4 rv[4];
  auto issue_tile = [&](const uint16_t* src, int rowstride) {
    #pragma unroll
    for (int it = 0; it < 4; it++) {
      int c = tid + (it << 9);
      int row = c >> 5, sl = c & 31;
      rv[it] = *(const u32x4*)(src + (size_t)row * rowstride + sl * 8);
    }
  };
  auto commit_tile = [&]() {
    #pragma unroll
    for (int it = 0; it < 4; it++) {
      int c = tid + (it << 9);
      int row = c >> 5, sl = c & 31;
      *(u32x4*)(stage + row * 512 + ((sl ^ (row & 7)) << 4)) = rv[it];
    }
  };
  auto frag = [&](int row, int slot) -> bf16x8 {
    u32x4 v = *(const u32x4*)(stage + row * 512 + ((slot ^ (row & 7)) << 4));
    return __builtin_bit_cast(bf16x8, v);
  };

  issue_tile(WT + (size_t)(h*256) * 256, 256);
  bf16x8 qx[8];
  #pragma unroll
  for (int ks = 0; ks < 8; ks++)
    qx[ks] = ld16(Xb + (size_t)(q0g + ln) * 256 + ks*32 + g*8);
  f32x4 qacc[16];
  #pragma unroll
  for (int f = 0; f < 16; f++) qacc[f] = (f32x4){0.f,0.f,0.f,0.f};
  #pragma unroll
  for (int t = 0; t < 4; t++) {
    __syncthreads();
    commit_tile();
    __syncthreads();
    if (t < 3) issue_tile(WT + (size_t)(h*256 + (t+1)*64) * 256, 256);
    #pragma unroll
    for (int ks = 0; ks < 8; ks++)
      #pragma unroll
      for (int f2 = 0; f2 < 4; f2++)
        qacc[t*4+f2] = MFMA16(qx[ks], frag(f2*16 + ln, ks*4 + g), qacc[t*4+f2]);
  }
  issue_tile(Kw + kvbase, 256);
  #pragma unroll
  for (int f = 0; f < 16; f++) {
    float bb = Bi[bt*2048 + h*256 + f*16 + ln];
    #pragma unroll
    for (int r = 0; r < 4; r++) qacc[f][r] = (qacc[f][r] + bb) * 0.0625f;
  }
  bf16x8 qa[8];
  #pragma unroll
  for (int dh = 0; dh < 2; dh++) {
    #pragma unroll
    for (int f2 = 0; f2 < 8; f2++) {
      int f = dh*8 + f2;
      #pragma unroll
      for (int r = 0; r < 4; r++)
        bounce_w2(slab, g*4 + r, f2*16 + ln, f2bf(qacc[f][r]));
    }
    #pragma unroll
    for (int ks2 = 0; ks2 < 4; ks2++)
      qa[dh*4 + ks2] = bounce_r16(slab, ln, ks2*4 + g);
  }

  f32x4 S[16];
  #pragma unroll
  for (int f = 0; f < 16; f++) S[f] = (f32x4){0.f,0.f,0.f,0.f};
  #pragma unroll
  for (int t = 0; t < 4; t++) {
    __syncthreads();
    commit_tile();
    __syncthreads();
    if (t < 3) issue_tile(Kw + kvbase + (size_t)((t+1)*64) * 256, 256);
    #pragma unroll
    for (int ks = 0; ks < 8; ks++)
      #pragma unroll
      for (int f2 = 0; f2 < 4; f2++)
        S[t*4+f2] = MFMA16(qa[ks], frag(f2*16 + ln, ks*4 + g), S[t*4+f2]);
  }
  issue_tile(Vt + kvbase, 256);

  #pragma unroll
  for (int r = 0; r < 4; r++) {
    float mx = -3.4e38f;
    #pragma unroll
    for (int f = 0; f < 16; f++) mx = fmaxf(mx, S[f][r]);
    #pragma unroll
    for (int m_ = 1; m_ < 16; m_ <<= 1) mx = fmaxf(mx, __shfl_xor(mx, m_, 64));
    float sum = 0.f;
    #pragma unroll
    for (int f = 0; f < 16; f++) {
      float p = __expf(S[f][r] - mx);
      S[f][r] = p; sum += p;
    }
    #pragma unroll
    for (int m_ = 1; m_ < 16; m_ <<= 1) sum += __shfl_xor(sum, m_, 64);
    float inv = 1.f / sum;
    #pragma unroll
    for (int f = 0; f < 16; f++) S[f][r] *= inv;
  }

  bf16x8 pb[8];
  #pragma unroll
  for (int kh = 0; kh < 2; kh++) {
    #pragma unroll
    for (int f2 = 0; f2 < 8; f2++) {
      int f = kh*8 + f2;
      #pragma unroll
      for (int r = 0; r < 4; r++)
        bounce_w2(slab, g*4 + r, f2*16 + ln, f2bf(S[f][r]));
    }
    #pragma unroll
    for (int ks2 = 0; ks2 < 4; ks2++)
      pb[kh*4 + ks2] = bounce_r16(slab, ln, ks2*4 + g);
  }

  f32x4 O[16];
  #pragma unroll
  for (int df = 0; df < 16; df++) O[df] = (f32x4){0.f,0.f,0.f,0.f};
  #pragma unroll
  for (int t = 0; t < 4; t++) {
    __syncthreads();
    commit_tile();
    __syncthreads();
    if (t < 3) issue_tile(Vt + kvbase + (size_t)((t+1)*64) * 256, 256);
    #pragma unroll
    for (int ks = 0; ks < 8; ks++)
      #pragma unroll
      for (int df2 = 0; df2 < 4; df2++)
        O[t*4+df2] = MFMA16(frag(df2*16 + ln, ks*4 + g), pb[ks], O[t*4+df2]);
  }
  issue_tile(WoT + (size_t)0 * 2048 + h*256, 2048);

  bf16x8 oa[8];
  #pragma unroll
  for (int dh = 0; dh < 2; dh++) {
    #pragma unroll
    for (int df2 = 0; df2 < 8; df2++) {
      int df = dh*8 + df2;
      #pragma unroll
      for (int r = 0; r < 4; r++)
        bounce_w2(slab, ln, df2*16 + g*4 + r, f2bf(O[df][r]));
    }
    #pragma unroll
    for (int ks2 = 0; ks2 < 4; ks2++)
      oa[dh*4 + ks2] = bounce_r16(slab, ln, ks2*4 + g);
  }

  f32x4 oacc[16];
  #pragma unroll
  for (int ef = 0; ef < 16; ef++) oacc[ef] = (f32x4){0.f,0.f,0.f,0.f};
  #pragma unroll
  for (int t = 0; t < 4; t++) {
    __syncthreads();
    commit_tile();
    __syncthreads();
    if (t < 3) issue_tile(WoT + (size_t)((t+1)*64) * 2048 + h*256, 2048);
    #pragma unroll
    for (int ks = 0; ks < 8; ks++)
      #pragma unroll
      for (int ef2 = 0; ef2 < 4; ef2++)
        oacc[t*4+ef2] = MFMA16(oa[ks], frag(ef2*16 + ln, ks*4 + g), oacc[t*4+ef2]);
  }
  #pragma unroll
  for (int ef = 0; ef < 16; ef++)
    #pragma unroll
    for (int r = 0; r < 4; r++)
      atomicAdd(out + (size_t)(q0g + g*4 + r) * 256 + ef*16 + ln, oacc[ef][r]);
}

// ---------------- launcher ----------------
extern "C" void kernel_launch(void* const* d_in, const int* in_sizes, int n_in,
                              void* d_out, int out_size, void* d_ws, size_t ws_size,
                              hipStream_t stream) {
  float* out = (float*)d_out;
  if (ws_size < WS_NEED) {
    sentinel_kernel<<<16384, 256, 0, stream>>>(out, 1000.0f + (float)(ws_size >> 20));
    return;
  }
  const float* x   = (const float*)d_in[0];
  const float* te  = (const float*)d_in[1];
  const float* re  = (const float*)d_in[2];
  const float* Wq  = (const float*)d_in[3];
  const float* Wk  = (const float*)d_in[4];
  const float* Wv  = (const float*)d_in[5];
  const float* Wqt = (const float*)d_in[6];
  const float* bqt = (const float*)d_in[7];
  const float* Wkt = (const float*)d_in[8];
  const float* bkt = (const float*)d_in[9];
  const float* Wvt = (const float*)d_in[10];
  const float* bvt = (const float*)d_in[11];
  const float* Wo  = (const float*)d_in[12];
  const float* bo  = (const float*)d_in[13];
  char* ws = (char*)d_ws;
  uint16_t* Xb  = (uint16_t*)(ws + OFF_XB);
  uint16_t* WT  = (uint16_t*)(ws + OFF_WT);
  uint16_t* WTT = (uint16_t*)(ws + OFF_WTT);
  uint16_t* WoT = (uint16_t*)(ws + OFF_WOT);
  uint16_t* Mb  = (uint16_t*)(ws + OFF_MB);
  float*    Bi  = (float*)(ws + OFF_BIAS);
  uint16_t* Kw  = (uint16_t*)(ws + OFF_K);
  uint16_t* Vt  = (uint16_t*)(ws + OFF_VT);

  prep_all<<<7744, 256, 0, stream>>>(te, re, Mb, x, Xb,
                                     Wq, Wk, Wv, Wqt, Wkt, Wvt, Wo, WT, WTT, WoT);
  bias_gemm<<<48, 256, 0, stream>>>(Mb, WTT, bqt, bkt, bvt, Bi);

  if (ws_size >= WS_NEED2) {
    // full pipeline: QKV GEMM (BM=256 shared-B) + attn core + output GEMM
    uint16_t* Qw = (uint16_t*)(ws + OFF_Q);
    qkv_gemm5<<<3072, 256, 0, stream>>>(Xb, WT, Bi, Kw, Vt, Qw);
    attn_core2<<<512, 1024, 0, stream>>>(Qw, Kw, Vt, Qw);
    out_gemm<<<512, 256, 0, stream>>>(Qw, WoT, bo, out);
  } else {
    // fallback: K,V only (grid 2048 -> z2 in {0,1}; Qw arg never dereferenced)
    qkv_gemm5<<<2048, 256, 0, stream>>>(Xb, WT, Bi, Kw, Vt, Kw);
    init_out<<<16384, 256, 0, stream>>>(bo, out);
    attn_v5<<<1024, 512, 0, stream>>>(Xb, WT, Bi, Kw, Vt, WoT, out);
  }
}

// Round 22
// 206.516 us; speedup vs baseline: 1.2627x; 1.2627x over previous
//
#include <hip/hip_runtime.h>
#include <stdint.h>

typedef __bf16 bf16x8 __attribute__((ext_vector_type(8)));
typedef float f32x4 __attribute__((ext_vector_type(4)));
typedef uint32_t u32x4 __attribute__((ext_vector_type(4)));

#define MFMA16(a,b,c) __builtin_amdgcn_mfma_f32_16x16x32_bf16(a,b,c,0,0,0)

// ---------------- workspace layout (bytes) ----------------
#define OFF_XB   0ull           // X bf16 [16384][256]              8,388,608
#define OFF_WT   8388608ull     // WqT/WkT/WvT bf16 [3][2048][256]  3,145,728
#define OFF_WTT  11534336ull    // Wq_tT/Wk_tT/Wv_tT same           3,145,728
#define OFF_WOT  14680064ull    // WoT bf16 [256][2048]             1,048,576
#define OFF_MB   15728640ull    // mish(t+r) bf16 [64][256]            32,768
#define OFF_BIAS 15761408ull    // bias fp32 [3][64][2048]          1,572,864
#define OFF_K    17334272ull    // K bf16 [512][256 l][256 d]      67,108,864
#define OFF_VT   84443136ull    // V^T bf16 [512][256 d][256 l]    67,108,864
#define WS_NEED  151552000ull   // minimum (fallback path)
#define OFF_Q    151552000ull   // Q bf16 [512][256 l][256 d] -- O overwrites in place
#define WS_NEED2 218660864ull   // full pipeline (confirmed available in r10)

__device__ __forceinline__ uint16_t f2bf(float f) {
  uint32_t u = __builtin_bit_cast(uint32_t, f);
  return (uint16_t)((u + 0x7fffu + ((u >> 16) & 1u)) >> 16);
}
__device__ __forceinline__ bf16x8 ld16(const uint16_t* p) {
  u32x4 v = *(const u32x4*)p;
  return __builtin_bit_cast(bf16x8, v);
}
// async global->LDS, 16B per lane; LDS dest is wave-uniform base + lane*16
__device__ __forceinline__ void gll16(const uint16_t* g, char* l) {
  __builtin_amdgcn_global_load_lds(
      (const __attribute__((address_space(1))) void*)g,
      (__attribute__((address_space(3))) void*)l, 16, 0, 0);
}
// per-wave 4KB bounce slab (fallback attn): [16 rows][128 bf16], pitch 256B, swz
__device__ __forceinline__ void bounce_w2(char* slab, int row, int col, uint16_t val) {
  int slot = col >> 3;
  *(uint16_t*)(slab + row * 256 + (((slot ^ (row & 7)) & 15) << 4) + ((col & 7) << 1)) = val;
}
__device__ __forceinline__ bf16x8 bounce_r16(const char* slab, int row, int slot) {
  u32x4 v = *(const u32x4*)(slab + row * 256 + (((slot ^ (row & 7)) & 15) << 4));
  return __builtin_bit_cast(bf16x8, v);
}

// ---------------- ws-size sentinel + output init ----------------
__global__ void sentinel_kernel(float* out, float val) {
  out[blockIdx.x * 256 + threadIdx.x] = val;
}
__global__ void init_out(const float* bo, float* out) {
  int i = blockIdx.x * 256 + threadIdx.x;
  out[i] = bo[i & 255];
}

// ---------------- fused prep: mish + convx + wtrans in one launch ----------------
__global__ void prep_all(const float* te, const float* re, uint16_t* mb,
                         const float* x, uint16_t* xb,
                         const float* w0, const float* w1, const float* w2,
                         const float* w3, const float* w4, const float* w5,
                         const float* w6, uint16_t* wt, uint16_t* wtt, uint16_t* wot) {
  int b = blockIdx.x;
  if (b < 64) {
    int i = b * 256 + threadIdx.x;
    float v = te[i] + re[i];
    float sp = log1pf(__expf(v));
    mb[i] = f2bf(v * tanhf(sp));
    return;
  }
  if (b < 4160) {
    int i = (b - 64) * 256 + threadIdx.x;
    float4 v = ((const float4*)x)[i];
    ushort4 o = make_ushort4(f2bf(v.x), f2bf(v.y), f2bf(v.z), f2bf(v.w));
    ((ushort4*)xb)[i] = o;
    return;
  }
  int local = b - 4160;
  int z = local >> 9, bx = local & 511;
  const float* src; uint16_t* dst; int C;
  if (z < 3)      { src = (z==0)?w0:((z==1)?w1:w2); dst = wt  + (size_t)z*524288;     C=2048; }
  else if (z < 6) { src = (z==3)?w3:((z==4)?w4:w5); dst = wtt + (size_t)(z-3)*524288; C=2048; }
  else            { src = w6; dst = wot;                                              C=256; }
  int R = (z < 6) ? 256 : 2048;
  __shared__ uint16_t tile[32][33];
  int tc = C >> 5;
  int bR = (bx / tc) << 5, bC = (bx % tc) << 5;
  int tx = threadIdx.x & 31, ty = threadIdx.x >> 5;  // 32 x 8
  #pragma unroll
  for (int i = 0; i < 4; i++) {
    int r = bR + ty + i * 8;
    tile[ty + i * 8][tx] = f2bf(src[(size_t)r * C + bC + tx]);
  }
  __syncthreads();
  #pragma unroll
  for (int i = 0; i < 4; i++) {
    int c = bC + ty + i * 8;
    dst[(size_t)c * R + bR + tx] = tile[tx][ty + i * 8];
  }
}

// ---------------- bias GEMM (no LDS): [3] x (m[64x256] @ Wt[256x2048] + b) -> fp32 ----------------
__global__ __launch_bounds__(256, 4)
void bias_gemm(const uint16_t* Mb, const uint16_t* WTT,
               const float* bq, const float* bk, const float* bv, float* biasAll) {
  int bid = blockIdx.x;            // 48 = 3 * 16
  int z = bid >> 4, nbt = bid & 15;
  int n0 = nbt << 7;
  const uint16_t* Bsrc = WTT + (size_t)z * 524288;
  const float* bvec = (z == 0) ? bq : ((z == 1) ? bk : bv);
  float* outp = biasAll + (size_t)z * 131072;
  int tid = threadIdx.x, lane = tid & 63, w = tid >> 6;
  int g = lane >> 4, ln = lane & 15;

  bf16x8 af[8];
  #pragma unroll
  for (int ks = 0; ks < 8; ks++)
    af[ks] = ld16(Mb + (size_t)(w*16 + ln) * 256 + ks*32 + g*8);
  f32x4 acc[8];
  #pragma unroll
  for (int j = 0; j < 8; j++) acc[j] = (f32x4){0.f,0.f,0.f,0.f};
  #pragma unroll
  for (int j = 0; j < 8; j++)
    #pragma unroll
    for (int ks = 0; ks < 8; ks++) {
      bf16x8 bf_ = ld16(Bsrc + (size_t)(n0 + j*16 + ln) * 256 + ks*32 + g*8);
      acc[j] = MFMA16(af[ks], bf_, acc[j]);
    }
  #pragma unroll
  for (int j = 0; j < 8; j++) {
    int colg = n0 + j*16 + ln;
    float bb = bvec[colg];
    #pragma unroll
    for (int r = 0; r < 4; r++)
      outp[(size_t)(w*16 + g*4 + r) * 2048 + colg] = acc[j][r] + bb;
  }
}

// ---------------- QKV GEMM (r20 proven): role-select hot loop + bounce epilogue, packed ----------------
// grid 6144 (full) or 4096 (fallback: K,V only). block 256, 4 waves.
__global__ __launch_bounds__(256)
void qkv_gemm4(const uint16_t* Xb, const uint16_t* WT, const float* biasAll,
               uint16_t* Kw, uint16_t* Vt, uint16_t* Qw) {
  __shared__ char stage[32768];
  int nwg = gridDim.x, cpx = nwg >> 3;
  int b0 = blockIdx.x;
  int bid = (b0 & 7) * cpx + (b0 >> 3);    // XCD-aware bijective swizzle
  int z2 = bid >> 11, rem = bid & 2047;    // z2: 0=K, 1=V, 2=Q
  int widx = (z2 + 1) % 3;                 // weight: 1=Wk, 2=Wv, 0=Wq
  int mb = rem >> 4, nb = rem & 15;
  int m0 = mb << 7, n0 = nb << 7;
  const uint16_t* Bsrc = WT + (size_t)widx * 524288;
  int bt = m0 >> 8;
  const float* bias = biasAll + (size_t)widx * 131072 + (size_t)bt * 2048;
  int tid = threadIdx.x, lane = tid & 63, w = tid >> 6;
  int g = lane >> 4, ln = lane & 15;
  int wr = w >> 1, wc = w & 1;             // wave quadrant: X rows wr*64, W rows wc*64
  int rw = lane >> 3;
  int sg = (lane & 7) ^ rw;                // source-swizzled 16B slot

  bool isV = (z2 == 1);
  const char* SA = isV ? stage           : (stage + 16384);  // m-side operand stage
  const char* SB = isV ? (stage + 16384) : stage;            // n-side operand stage
  int RA = isV ? wr*64 : wc*64;
  int RB = isV ? wc*64 : wr*64;

  f32x4 acc[4][4];
  #pragma unroll
  for (int u = 0; u < 4; u++)
    #pragma unroll
    for (int v = 0; v < 4; v++) acc[u][v] = (f32x4){0.f,0.f,0.f,0.f};

  for (int kt = 0; kt < 4; kt++) {
    int k0 = kt << 6;
    __syncthreads();
    #pragma unroll
    for (int c = 0; c < 4; c++) {          // each wave stages 4KB of X + 4KB of W
      int chunk = w * 4 + c;
      int row = chunk * 8 + rw;
      gll16(Xb   + (size_t)(m0 + row) * 256 + k0 + sg * 8, stage + chunk * 1024);
      gll16(Bsrc + (size_t)(n0 + row) * 256 + k0 + sg * 8, stage + 16384 + chunk * 1024);
    }
    __syncthreads();                       // compiler drains vmcnt before barrier
    #pragma unroll
    for (int ks = 0; ks < 2; ks++) {
      bf16x8 fa[4], fb[4];
      #pragma unroll
      for (int u = 0; u < 4; u++) {
        int R = RA + u*16 + ln;
        u32x4 x = *(const u32x4*)(SA + R*128 + ((((ks<<2)+g) ^ (R & 7)) << 4));
        fa[u] = __builtin_bit_cast(bf16x8, x);
      }
      #pragma unroll
      for (int v = 0; v < 4; v++) {
        int R = RB + v*16 + ln;
        u32x4 x = *(const u32x4*)(SB + R*128 + ((((ks<<2)+g) ^ (R & 7)) << 4));
        fb[v] = __builtin_bit_cast(bf16x8, x);
      }
      #pragma unroll
      for (int v = 0; v < 4; v++)
        #pragma unroll
        for (int u = 0; u < 4; u++) acc[u][v] = MFMA16(fa[u], fb[v], acc[u][v]);
    }
  }

  // ---- epilogue: bounce through per-wave 8KB slab, all packed 8B writes ----
  __syncthreads();
  char* esl = stage + (w << 13);           // [64 rows][64 cols] bf16, pitch 128B, swz slots
  int hh = n0 >> 8;
  size_t hb = (size_t)(bt * 8 + hh) << 16;
  int dbase = (n0 & 255) + wc*64;
  int lbase = (m0 & 255) + wr*64;

  if (isV) {
    #pragma unroll
    for (int v = 0; v < 4; v++) {
      float bb = bias[n0 + wc*64 + v*16 + ln];
      int row = v*16 + ln;
      #pragma unroll
      for (int u = 0; u < 4; u++) {
        int col0 = u*16 + g*4;
        ushort4 pk = make_ushort4(f2bf(acc[u][v][0]+bb), f2bf(acc[u][v][1]+bb),
                                  f2bf(acc[u][v][2]+bb), f2bf(acc[u][v][3]+bb));
        *(ushort4*)(esl + row*128 + ((((col0 >> 3) ^ (row & 7)) & 7) << 4)
                    + ((col0 & 7) << 1)) = pk;
      }
    }
  } else {
    float scale = (z2 == 2) ? 0.0625f : 1.0f;
    #pragma unroll
    for (int u = 0; u < 4; u++) {
      float4 b4 = *(const float4*)(bias + n0 + wc*64 + u*16 + g*4);
      #pragma unroll
      for (int v = 0; v < 4; v++) {
        int row = v*16 + ln;
        int col0 = u*16 + g*4;
        ushort4 pk = make_ushort4(f2bf((acc[u][v][0]+b4.x)*scale),
                                  f2bf((acc[u][v][1]+b4.y)*scale),
                                  f2bf((acc[u][v][2]+b4.z)*scale),
                                  f2bf((acc[u][v][3]+b4.w)*scale));
        *(ushort4*)(esl + row*128 + ((((col0 >> 3) ^ (row & 7)) & 7) << 4)
                    + ((col0 & 7) << 1)) = pk;
      }
    }
  }
  // same-wave coalesced readback: 8 x 16B stores per thread
  #pragma unroll
  for (int it = 0; it < 8; it++) {
    int idx = it*64 + lane;
    int row = idx >> 3, ch = idx & 7;
    u32x4 v = *(const u32x4*)(esl + row*128 + (((ch ^ (row & 7)) & 7) << 4));
    if (isV) {          // V^T: [d][l]
      *(u32x4*)(Vt + hb + ((size_t)(dbase + row) << 8) + lbase + ch*8) = v;
    } else {            // K/Q: [l][d]
      uint16_t* dst = (z2 == 0) ? Kw : Qw;
      *(u32x4*)(dst + hb + ((size_t)(lbase + row) << 8) + dbase + ch*8) = v;
    }
  }
}

// ---------------- attn core v2 (proven): reg-staged K/V; O overwrites Q in place ----------------
__global__ __launch_bounds__(1024, 2)
void attn_core2(const uint16_t* Qw, const uint16_t* Kw, const uint16_t* Vt, uint16_t* Ob) {
  __shared__ char smem[65536];
  int tid = threadIdx.x, lane = tid & 63, w = tid >> 6;   // w in 0..15
  int g = lane >> 4, ln = lane & 15;
  int bh = blockIdx.x;                       // 512 blocks
  const size_t kvbase = (size_t)bh << 16;
  int q0l = w * 16;
  char* stage = smem;
  char* slab  = smem + 32768 + (w << 11);

  u32x4 rv[2];
  auto issue_tile = [&](const uint16_t* src) {
    #pragma unroll
    for (int it = 0; it < 2; it++) {
      int c = tid + (it << 10);
      int row = c >> 5, sl = c & 31;
      rv[it] = *(const u32x4*)(src + (size_t)row * 256 + sl * 8);
    }
  };
  auto commit_tile = [&]() {
    #pragma unroll
    for (int it = 0; it < 2; it++) {
      int c = tid + (it << 10);
      int row = c >> 5, sl = c & 31;
      *(u32x4*)(stage + row * 512 + ((sl ^ (row & 7)) << 4)) = rv[it];
    }
  };
  auto frag = [&](int row, int slot) -> bf16x8 {
    u32x4 v = *(const u32x4*)(stage + row * 512 + ((slot ^ (row & 7)) << 4));
    return __builtin_bit_cast(bf16x8, v);
  };

  issue_tile(Kw + kvbase);
  bf16x8 qa[8];
  #pragma unroll
  for (int ks = 0; ks < 8; ks++)
    qa[ks] = ld16(Qw + kvbase + (size_t)(q0l + ln) * 256 + ks*32 + g*8);

  f32x4 S[16];
  #pragma unroll
  for (int f = 0; f < 16; f++) S[f] = (f32x4){0.f,0.f,0.f,0.f};
  #pragma unroll
  for (int t = 0; t < 4; t++) {
    __syncthreads();
    commit_tile();
    __syncthreads();
    if (t < 3) issue_tile(Kw + kvbase + (size_t)((t+1)*64) * 256);
    #pragma unroll
    for (int ks = 0; ks < 8; ks++)
      #pragma unroll
      for (int f2 = 0; f2 < 4; f2++)
        S[t*4+f2] = MFMA16(qa[ks], frag(f2*16 + ln, ks*4 + g), S[t*4+f2]);
  }
  issue_tile(Vt + kvbase);

  #pragma unroll
  for (int r = 0; r < 4; r++) {
    float mx = -3.4e38f;
    #pragma unroll
    for (int f = 0; f < 16; f++) mx = fmaxf(mx, S[f][r]);
    #pragma unroll
    for (int m_ = 1; m_ < 16; m_ <<= 1) mx = fmaxf(mx, __shfl_xor(mx, m_, 64));
    float sum = 0.f;
    #pragma unroll
    for (int f = 0; f < 16; f++) {
      float p = __expf(S[f][r] - mx);
      S[f][r] = p; sum += p;
    }
    #pragma unroll
    for (int m_ = 1; m_ < 16; m_ <<= 1) sum += __shfl_xor(sum, m_, 64);
    float inv = 1.f / sum;
    #pragma unroll
    for (int f = 0; f < 16; f++) S[f][r] *= inv;
  }

  bf16x8 pb[8];
  #pragma unroll
  for (int qtr = 0; qtr < 4; qtr++) {
    #pragma unroll
    for (int f2 = 0; f2 < 4; f2++) {
      int col = f2*16 + ln;
      int slot = col >> 3;
      #pragma unroll
      for (int r = 0; r < 4; r++) {
        int row = g*4 + r;
        *(uint16_t*)(slab + row*128 + (((slot ^ (row & 7)) & 7) << 4) + ((col & 7) << 1))
            = f2bf(S[qtr*4+f2][r]);
      }
    }
    #pragma unroll
    for (int i = 0; i < 2; i++) {
      u32x4 v = *(const u32x4*)(slab + ln*128 + ((((i*4+g) ^ (ln & 7)) & 7) << 4));
      pb[qtr*2+i] = __builtin_bit_cast(bf16x8, v);
    }
  }

  f32x4 O[16];
  #pragma unroll
  for (int df = 0; df < 16; df++) O[df] = (f32x4){0.f,0.f,0.f,0.f};
  #pragma unroll
  for (int t = 0; t < 4; t++) {
    __syncthreads();
    commit_tile();
    __syncthreads();
    if (t < 3) issue_tile(Vt + kvbase + (size_t)((t+1)*64) * 256);
    #pragma unroll
    for (int ks = 0; ks < 8; ks++)
      #pragma unroll
      for (int df2 = 0; df2 < 4; df2++)
        O[t*4+df2] = MFMA16(frag(df2*16 + ln, ks*4 + g), pb[ks], O[t*4+df2]);
  }

  size_t obase = kvbase + (size_t)(q0l + ln) * 256;
  #pragma unroll
  for (int df = 0; df < 16; df++) {
    ushort4 pk = make_ushort4(f2bf(O[df][0]), f2bf(O[df][1]), f2bf(O[df][2]), f2bf(O[df][3]));
    *(ushort4*)(Ob + obase + df*16 + g*4) = pk;
  }
}

// ---------------- out GEMM: O (bh,l,d) @ Wo + bo -> fp32 out; A+B prefetched; XCD swizzle ----------------
__global__ __launch_bounds__(256, 4)
void out_gemm(const uint16_t* Ob, const uint16_t* WoT, const float* bo, float* out) {
  __shared__ char stage[16384];
  int b0 = blockIdx.x;
  int bid = (b0 & 7) * 64 + (b0 >> 3);
  int mt = bid >> 1, nt = bid & 1;
  int m0 = mt << 6, n0 = nt << 7;
  int bt = m0 >> 8;
  int lrow = (m0 & 255);
  int tid = threadIdx.x, lane = tid & 63, w = tid >> 6;
  int g = lane >> 4, ln = lane & 15;

  u32x4 rb[4];
  auto issueW = [&](int kt) {
    #pragma unroll
    for (int it = 0; it < 4; it++) {
      int c = tid + (it << 8);
      int row = c >> 3, sl = c & 7;
      rb[it] = *(const u32x4*)(WoT + (size_t)(n0 + row) * 2048 + kt*64 + sl*8);
    }
  };
  auto aptr = [&](int kt) -> const uint16_t* {
    return Ob + ((size_t)(bt*8 + (kt >> 2)) << 16)
         + (size_t)(lrow + w*16 + ln) * 256 + (kt & 3) * 64;
  };
  issueW(0);
  bf16x8 afc[2];
  { const uint16_t* ab = aptr(0); afc[0] = ld16(ab + g*8); afc[1] = ld16(ab + 32 + g*8); }
  f32x4 acc[8];
  #pragma unroll
  for (int j = 0; j < 8; j++) acc[j] = (f32x4){0.f,0.f,0.f,0.f};

  for (int kt = 0; kt < 32; kt++) {
    __syncthreads();
    #pragma unroll
    for (int it = 0; it < 4; it++) {
      int c = tid + (it << 8);
      int row = c >> 3, sl = c & 7;
      *(u32x4*)(stage + row*128 + (((sl ^ (row & 7)) & 7) << 4)) = rb[it];
    }
    __syncthreads();
    bf16x8 afn[2];
    if (kt < 31) {
      issueW(kt+1);
      const uint16_t* ab = aptr(kt+1);
      afn[0] = ld16(ab + g*8); afn[1] = ld16(ab + 32 + g*8);
    }
    #pragma unroll
    for (int ks = 0; ks < 2; ks++)
      #pragma unroll
      for (int j = 0; j < 8; j++) {
        int row = j*16 + ln;
        u32x4 v = *(const u32x4*)(stage + row*128 + ((((ks*4+g) ^ (row & 7)) & 7) << 4));
        acc[j] = MFMA16(afc[ks], __builtin_bit_cast(bf16x8, v), acc[j]);
      }
    if (kt < 31) { afc[0] = afn[0]; afc[1] = afn[1]; }
  }
  #pragma unroll
  for (int j = 0; j < 8; j++) {
    int col = n0 + j*16 + ln;
    float bb = bo[col];
    #pragma unroll
    for (int r = 0; r < 4; r++)
      out[(size_t)(m0 + w*16 + g*4 + r) * 256 + col] = acc[j][r] + bb;
  }
}

// ---------------- fallback fused attention (proven round-9 path) ----------------
__global__ __launch_bounds__(512, 2)
void attn_v5(const uint16_t* Xb, const uint16_t* WT, const float* Bi,
             const uint16_t* Kw, const uint16_t* Vt, const uint16_t* WoT,
             float* out) {
  __shared__ char smem[65536];
  int tid = threadIdx.x, lane = tid & 63, w = tid >> 6;
  int g = lane >> 4, ln = lane & 15;
  int bid = blockIdx.x;
  int bh = bid >> 1, qh = bid & 1;
  int bt = bh >> 3, h = bh & 7;
  const size_t kvbase = (size_t)bh << 16;
  int q0g = bt * 256 + qh * 128 + w * 16;
  char* stage = smem;
  char* slab  = smem + 32768 + (w << 12);

  u32x4 rv[4];
  auto issue_tile = [&](const uint16_t* src, int rowstride) {
    #pragma unroll
    for (int it = 0; it < 4; it++) {
      int c = tid + (it << 9);
      int row = c >> 5, sl = c & 31;
      rv[it] = *(const u32x4*)(src + (size_t)row * rowstride + sl * 8);
    }
  };
  auto commit_tile = [&]() {
    #pragma unroll
    for (int it = 0; it < 4; it++) {
      int c = tid + (it << 9);
      int row = c >> 5, sl = c & 31;
      *(u32x4*)(stage + row * 512 + ((sl ^ (row & 7)) << 4)) = rv[it];
    }
  };
  auto frag = [&](int row, int slot) -> bf16x8 {
    u32x4 v = *(const u32x4*)(stage + row * 512 + ((slot ^ (row & 7)) << 4));
    return __builtin_bit_cast(bf16x8, v);
  };

  issue_tile(WT + (size_t)(h*256) * 256, 256);
  bf16x8 qx[8];
  #pragma unroll
  for (int ks = 0; ks < 8; ks++)
    qx[ks] = ld16(Xb + (size_t)(q0g + ln) * 256 + ks*32 + g*8);
  f32x4 qacc[16];
  #pragma unroll
  for (int f = 0; f < 16; f++) qacc[f] = (f32x4){0.f,0.f,0.f,0.f};
  #pragma unroll
  for (int t = 0; t < 4; t++) {
    __syncthreads();
    commit_tile();
    __syncthreads();
    if (t < 3) issue_tile(WT + (size_t)(h*256 + (t+1)*64) * 256, 256);
    #pragma unroll
    for (int ks = 0; ks < 8; ks++)
      #pragma unroll
      for (int f2 = 0; f2 < 4; f2++)
        qacc[t*4+f2] = MFMA16(qx[ks], frag(f2*16 + ln, ks*4 + g), qacc[t*4+f2]);
  }
  issue_tile(Kw + kvbase, 256);
  #pragma unroll
  for (int f = 0; f < 16; f++) {
    float bb = Bi[bt*2048 + h*256 + f*16 + ln];
    #pragma unroll
    for (int r = 0; r < 4; r++) qacc[f][r] = (qacc[f][r] + bb) * 0.0625f;
  }
  bf16x8 qa[8];
  #pragma unroll
  for (int dh = 0; dh < 2; dh++) {
    #pragma unroll
    for (int f2 = 0; f2 < 8; f2++) {
      int f = dh*8 + f2;
      #pragma unroll
      for (int r = 0; r < 4; r++)
        bounce_w2(slab, g*4 + r, f2*16 + ln, f2bf(qacc[f][r]));
    }
    #pragma unroll
    for (int ks2 = 0; ks2 < 4; ks2++)
      qa[dh*4 + ks2] = bounce_r16(slab, ln, ks2*4 + g);
  }

  f32x4 S[16];
  #pragma unroll
  for (int f = 0; f < 16; f++) S[f] = (f32x4){0.f,0.f,0.f,0.f};
  #pragma unroll
  for (int t = 0; t < 4; t++) {
    __syncthreads();
    commit_tile();
    __syncthreads();
    if (t < 3) issue_tile(Kw + kvbase + (size_t)((t+1)*64) * 256, 256);
    #pragma unroll
    for (int ks = 0; ks < 8; ks++)
      #pragma unroll
      for (int f2 = 0; f2 < 4; f2++)
        S[t*4+f2] = MFMA16(qa[ks], frag(f2*16 + ln, ks*4 + g), S[t*4+f2]);
  }
  issue_tile(Vt + kvbase, 256);

  #pragma unroll
  for (int r = 0; r < 4; r++) {
    float mx = -3.4e38f;
    #pragma unroll
    for (int f = 0; f < 16; f++) mx = fmaxf(mx, S[f][r]);
    #pragma unroll
    for (int m_ = 1; m_ < 16; m_ <<= 1) mx = fmaxf(mx, __shfl_xor(mx, m_, 64));
    float sum = 0.f;
    #pragma unroll
    for (int f = 0; f < 16; f++) {
      float p = __expf(S[f][r] - mx);
      S[f][r] = p; sum += p;
    }
    #pragma unroll
    for (int m_ = 1; m_ < 16; m_ <<= 1) sum += __shfl_xor(sum, m_, 64);
    float inv = 1.f / sum;
    #pragma unroll
    for (int f = 0; f < 16; f++) S[f][r] *= inv;
  }

  bf16x8 pb[8];
  #pragma unroll
  for (int kh = 0; kh < 2; kh++) {
    #pragma unroll
    for (int f2 = 0; f2 < 8; f2++) {
      int f = kh*8 + f2;
      #pragma unroll
      for (int r = 0; r < 4; r++)
        bounce_w2(slab, g*4 + r, f2*16 + ln, f2bf(S[f][r]));
    }
    #pragma unroll
    for (int ks2 = 0; ks2 < 4; ks2++)
      pb[kh*4 + ks2] = bounce_r16(slab, ln, ks2*4 + g);
  }

  f32x4 O[16];
  #pragma unroll
  for (int df = 0; df < 16; df++) O[df] = (f32x4){0.f,0.f,0.f,0.f};
  #pragma unroll
  for (int t = 0; t < 4; t++) {
    __syncthreads();
    commit_tile();
    __syncthreads();
    if (t < 3) issue_tile(Vt + kvbase + (size_t)((t+1)*64) * 256, 256);
    #pragma unroll
    for (int ks = 0; ks < 8; ks++)
      #pragma unroll
      for (int df2 = 0; df2 < 4; df2++)
        O[t*4+df2] = MFMA16(frag(df2*16 + ln, ks*4 + g), pb[ks], O[t*4+df2]);
  }
  issue_tile(WoT + (size_t)0 * 2048 + h*256, 2048);

  bf16x8 oa[8];
  #pragma unroll
  for (int dh = 0; dh < 2; dh++) {
    #pragma unroll
    for (int df2 = 0; df2 < 8; df2++) {
      int df = dh*8 + df2;
      #pragma unroll
      for (int r = 0; r < 4; r++)
        bounce_w2(slab, ln, df2*16 + g*4 + r, f2bf(O[df][r]));
    }
    #pragma unroll
    for (int ks2 = 0; ks2 < 4; ks2++)
      oa[dh*4 + ks2] = bounce_r16(slab, ln, ks2*4 + g);
  }

  f32x4 oacc[16];
  #pragma unroll
  for (int ef = 0; ef < 16; ef++) oacc[ef] = (f32x4){0.f,0.f,0.f,0.f};
  #pragma unroll
  for (int t = 0; t < 4; t++) {
    __syncthreads();
    commit_tile();
    __syncthreads();
    if (t < 3) issue_tile(WoT + (size_t)((t+1)*64) * 2048 + h*256, 2048);
    #pragma unroll
    for (int ks = 0; ks < 8; ks++)
      #pragma unroll
      for (int ef2 = 0; ef2 < 4; ef2++)
        oacc[t*4+ef2] = MFMA16(oa[ks], frag(ef2*16 + ln, ks*4 + g), oacc[t*4+ef2]);
  }
  #pragma unroll
  for (int ef = 0; ef < 16; ef++)
    #pragma unroll
    for (int r = 0; r < 4; r++)
      atomicAdd(out + (size_t)(q0g + g*4 + r) * 256 + ef*16 + ln, oacc[ef][r]);
}

// ---------------- launcher ----------------
extern "C" void kernel_launch(void* const* d_in, const int* in_sizes, int n_in,
                              void* d_out, int out_size, void* d_ws, size_t ws_size,
                              hipStream_t stream) {
  float* out = (float*)d_out;
  if (ws_size < WS_NEED) {
    sentinel_kernel<<<16384, 256, 0, stream>>>(out, 1000.0f + (float)(ws_size >> 20));
    return;
  }
  const float* x   = (const float*)d_in[0];
  const float* te  = (const float*)d_in[1];
  const float* re  = (const float*)d_in[2];
  const float* Wq  = (const float*)d_in[3];
  const float* Wk  = (const float*)d_in[4];
  const float* Wv  = (const float*)d_in[5];
  const float* Wqt = (const float*)d_in[6];
  const float* bqt = (const float*)d_in[7];
  const float* Wkt = (const float*)d_in[8];
  const float* bkt = (const float*)d_in[9];
  const float* Wvt = (const float*)d_in[10];
  const float* bvt = (const float*)d_in[11];
  const float* Wo  = (const float*)d_in[12];
  const float* bo  = (const float*)d_in[13];
  char* ws = (char*)d_ws;
  uint16_t* Xb  = (uint16_t*)(ws + OFF_XB);
  uint16_t* WT  = (uint16_t*)(ws + OFF_WT);
  uint16_t* WTT = (uint16_t*)(ws + OFF_WTT);
  uint16_t* WoT = (uint16_t*)(ws + OFF_WOT);
  uint16_t* Mb  = (uint16_t*)(ws + OFF_MB);
  float*    Bi  = (float*)(ws + OFF_BIAS);
  uint16_t* Kw  = (uint16_t*)(ws + OFF_K);
  uint16_t* Vt  = (uint16_t*)(ws + OFF_VT);

  prep_all<<<7744, 256, 0, stream>>>(te, re, Mb, x, Xb,
                                     Wq, Wk, Wv, Wqt, Wkt, Wvt, Wo, WT, WTT, WoT);
  bias_gemm<<<48, 256, 0, stream>>>(Mb, WTT, bqt, bkt, bvt, Bi);

  if (ws_size >= WS_NEED2) {
    // full pipeline: QKV GEMM (r20 proven) + attn core + output GEMM
    uint16_t* Qw = (uint16_t*)(ws + OFF_Q);
    qkv_gemm4<<<6144, 256, 0, stream>>>(Xb, WT, Bi, Kw, Vt, Qw);
    attn_core2<<<512, 1024, 0, stream>>>(Qw, Kw, Vt, Qw);
    out_gemm<<<512, 256, 0, stream>>>(Qw, WoT, bo, out);
  } else {
    // fallback: K,V only (grid 4096 -> no z2==2 blocks; Qw arg never dereferenced)
    qkv_gemm4<<<4096, 256, 0, stream>>>(Xb, WT, Bi, Kw, Vt, Kw);
    init_out<<<16384, 256, 0, stream>>>(bo, out);
    attn_v5<<<1024, 512, 0, stream>>>(Xb, WT, Bi, Kw, Vt, WoT, out);
  }
}